// Round 3
// baseline (411.698 us; speedup 1.0000x reference)
//
#include <hip/hip_runtime.h>

// W8A8 quantized linear on gfx950.
// R3 (2nd resubmit; rounds 1-2 were infra failures: acquisition timeout,
// then a Trio-nursery ExceptionGroup — no compile/correctness/perf signal):
// 256x256 tile, 8-wave deep-pipelined i8 GEMM (T3+T4+T5 port of the
// verified 256^2 schedule): 4 phases x 16 MFMA per K-tile with raw s_barrier,
// counted vmcnt (never 0 in main loop), setprio around MFMA clusters,
// double-buffered LDS (128 KB), prefetch burst 2 tiles ahead.
// Swizzle scheme (conflict-free, HW-verified in R2) unchanged.

using v4i = __attribute__((ext_vector_type(4))) int;

typedef const __attribute__((address_space(1))) signed char gc_t;
typedef __attribute__((address_space(3))) signed char lc_t;

constexpr int BM = 256;
constexpr int BN = 256;
constexpr int BK = 128;                  // int8 elements per K-tile (128 B rows)
constexpr int TILE_BYTES = BM * BK;      // 32 KB per matrix per buffer

// ---- quantization ---------------------------------------------------------

__device__ __forceinline__ int quant4(const float4 f, float s) {
    int a = (int)fminf(fmaxf(f.x / s, -128.0f), 127.0f);
    int b = (int)fminf(fmaxf(f.y / s, -128.0f), 127.0f);
    int c = (int)fminf(fmaxf(f.z / s, -128.0f), 127.0f);
    int d = (int)fminf(fmaxf(f.w / s, -128.0f), 127.0f);
    return (a & 0xff) | ((b & 0xff) << 8) | ((c & 0xff) << 16) | ((d & 0xff) << 24);
}

__global__ void quant_x_kernel(const float4* __restrict__ x,
                               const float* __restrict__ scale,
                               int* __restrict__ out, int n4) {
    const float s = scale[0];
    int i = blockIdx.x * blockDim.x + threadIdx.x;
    if (i >= n4) return;
    out[i] = quant4(x[i], s);
}

__global__ void quant_w_kernel(const float4* __restrict__ w,
                               int* __restrict__ out, int n4) {
    int i = blockIdx.x * blockDim.x + threadIdx.x;
    if (i >= n4) return;
    float4 f = w[i];
    out[i] = ((int)f.x & 0xff) | (((int)f.y & 0xff) << 8) |
             (((int)f.z & 0xff) << 16) | (((int)f.w & 0xff) << 24);
}

// ---- int8 GEMM ------------------------------------------------------------
//
// LDS swizzle (as R2, measured 0 bank conflicts): global_load_lds writes
// linearly (base + lane*16), so the GLOBAL source is pre-swizzled. LDS slot
// (row r, 16B-chunk c) holds global chunk (c ^ (r&7)). Staging covers 8 rows
// per wave per inst, so r&7 == lane>>3 and the source chunk is a pure lane
// function. Fragment ds_read_b128 XORs the chunk back.
//
// Pipeline: 2 LDS buffers, tile t in buf[t&1]. Loads for tile t+2 are issued
// only AFTER the barrier that ends tile t's compute (buffer free -> no race).
// Loop head waits vmcnt(8): tile t landed, tile t+1's 8 loads still in
// flight across all barriers. Raw s_barrier everywhere (no vmcnt(0) drain).

// per-wave stage of one 256x128 tile half (A or B): 4 insts x 8 rows
#define STAGE_TILE(dstbuf, kbyte)                                              \
    do {                                                                       \
        const signed char* _pa = pA + (size_t)(kbyte);                         \
        const signed char* _pb = pB + (size_t)(kbyte);                         \
        lc_t* _la = (lc_t*)(smem + (dstbuf) * (2 * TILE_BYTES) +               \
                            (wid * 8) * BK);                                   \
        lc_t* _lb = (lc_t*)(smem + (dstbuf) * (2 * TILE_BYTES) + TILE_BYTES +  \
                            (wid * 8) * BK);                                   \
        _Pragma("unroll")                                                      \
        for (int c = 0; c < 4; ++c) {                                          \
            __builtin_amdgcn_global_load_lds(                                  \
                (gc_t*)(_pa + (size_t)(c * 64) * Kz), _la + c * 64 * BK,       \
                16, 0, 0);                                                     \
            __builtin_amdgcn_global_load_lds(                                  \
                (gc_t*)(_pb + (size_t)(c * 64) * Kz), _lb + c * 64 * BK,       \
                16, 0, 0);                                                     \
        }                                                                      \
    } while (0)

__global__ __launch_bounds__(512, 2) void gemm_i8_kernel(
    const signed char* __restrict__ Aq,   // [M][K] int8
    const signed char* __restrict__ Wq,   // [N][K] int8
    const float* __restrict__ wscale,     // [N]
    const float* __restrict__ iscale,     // [1]
    const float* __restrict__ bias,       // [N]
    float* __restrict__ C,                // [M][N]
    int M, int N, int K)
{
    __shared__ signed char smem[2 * 2 * TILE_BYTES];   // 128 KB

    const int tid  = threadIdx.x;
    const int wid  = tid >> 6;            // 0..7
    const int lane = tid & 63;
    const int wm   = (wid >> 2) * 128;    // wave M offset (2 M-waves)
    const int wn   = (wid & 3) * 64;      // wave N offset (4 N-waves)

    // XCD-aware bijective block swizzle (nwg % 8 == 0 for our shapes)
    const int nwg = gridDim.x;
    int wg = blockIdx.x;
    if ((nwg & 7) == 0) wg = (wg & 7) * (nwg >> 3) + (wg >> 3);
    const int ntx = N / BN;
    const int m0 = (wg / ntx) * BM;
    const int n0 = (wg % ntx) * BN;

    // staging lane mapping (8 rows x 8 chunks per wave-inst)
    const int srow   = lane >> 3;                   // 0..7
    const int gchunk = (lane & 7) ^ srow;           // swizzled source chunk

    // MFMA fragment addressing (16x16x64 i8): row = lane&15, k-quarter = lane>>4
    const int fr = lane & 15;
    const int qh = lane >> 4;
    const int coff0 = ((0 * 4 + qh) ^ (fr & 7)) * 16;   // k-substep 0
    const int coff1 = ((1 * 4 + qh) ^ (fr & 7)) * 16;   // k-substep 1

    v4i acc[8][4];
#pragma unroll
    for (int i = 0; i < 8; ++i)
#pragma unroll
        for (int j = 0; j < 4; ++j) acc[i][j] = (v4i){0, 0, 0, 0};

    const size_t Kz = (size_t)K;
    const signed char* pA = Aq + (size_t)(m0 + wid * 8 + srow) * Kz + gchunk * 16;
    const signed char* pB = Wq + (size_t)(n0 + wid * 8 + srow) * Kz + gchunk * 16;

    const int NT = K / BK;                // 32 K-tiles

    // prologue: stage tiles 0 and 1 (8 loads each per wave)
    STAGE_TILE(0, 0);
    STAGE_TILE(1, BK);

    for (int t = 0; t < NT; ++t) {
        const int cur = t & 1;
        // tile t must be fully in LDS; tile t+1's 8 loads stay in flight
        if (t + 1 < NT) {
            asm volatile("s_waitcnt vmcnt(8)" ::: "memory");
        } else {
            asm volatile("s_waitcnt vmcnt(0)" ::: "memory");
        }
        __builtin_amdgcn_s_barrier();

        const signed char* Ab = smem + cur * (2 * TILE_BYTES);
        const signed char* Bb = Ab + TILE_BYTES;

        v4i bf[4][2];   // B frags cached for the whole K-tile (32 VGPR)
        v4i af[2][2];   // per-phase A slice

#pragma unroll
        for (int p = 0; p < 4; ++p) {
            if (p == 0) {
#pragma unroll
                for (int nt = 0; nt < 4; ++nt) {
                    const signed char* br = Bb + (size_t)(wn + nt * 16 + fr) * BK;
                    bf[nt][0] = *(const v4i*)(br + coff0);
                    bf[nt][1] = *(const v4i*)(br + coff1);
                }
            }
#pragma unroll
            for (int i = 0; i < 2; ++i) {
                const signed char* ar =
                    Ab + (size_t)(wm + (2 * p + i) * 16 + fr) * BK;
                af[i][0] = *(const v4i*)(ar + coff0);
                af[i][1] = *(const v4i*)(ar + coff1);
            }
            __builtin_amdgcn_s_barrier();
            __builtin_amdgcn_sched_barrier(0);
            __builtin_amdgcn_s_setprio(1);
#pragma unroll
            for (int s = 0; s < 2; ++s)
#pragma unroll
                for (int i = 0; i < 2; ++i)
#pragma unroll
                    for (int nt = 0; nt < 4; ++nt)
                        acc[2 * p + i][nt] = __builtin_amdgcn_mfma_i32_16x16x64_i8(
                            af[i][s], bf[nt][s], acc[2 * p + i][nt], 0, 0, 0);
            __builtin_amdgcn_s_setprio(0);
            __builtin_amdgcn_sched_barrier(0);
            __builtin_amdgcn_s_barrier();
        }

        // buf[cur] is now free: issue tile t+2 into it (8 loads/wave)
        if (t + 2 < NT) {
            asm volatile("" ::: "memory");
            STAGE_TILE(cur, (size_t)(t + 2) * BK);
            asm volatile("" ::: "memory");
        }
    }

    // ---- epilogue: dequant + bias ----
    // C/D layout (HW-verified): col = lane&15, row = qh*4 + reg
    const float is = iscale[0];
#pragma unroll
    for (int nt = 0; nt < 4; ++nt) {
        const int col = n0 + wn + nt * 16 + fr;
        const float sc = wscale[col] * is;
        const float bv = bias[col];
#pragma unroll
        for (int mt = 0; mt < 8; ++mt) {
            const size_t rbase = (size_t)(m0 + wm + mt * 16 + qh * 4);
#pragma unroll
            for (int r = 0; r < 4; ++r) {
                C[(rbase + r) * N + col] = (float)acc[mt][nt][r] * sc + bv;
            }
        }
    }
}

// ---- launch ---------------------------------------------------------------

extern "C" void kernel_launch(void* const* d_in, const int* in_sizes, int n_in,
                              void* d_out, int out_size, void* d_ws, size_t ws_size,
                              hipStream_t stream) {
    const float* x  = (const float*)d_in[0];   // [B,S,IN] fp32
    const float* qw = (const float*)d_in[1];   // [OUT,IN] fp32 (int8 values)
    const float* ws = (const float*)d_in[2];   // [OUT,1]
    const float* is = (const float*)d_in[3];   // [1]
    const float* bs = (const float*)d_in[4];   // [OUT]
    float* out = (float*)d_out;

    const int nx = in_sizes[0];   // M*K
    const int nw = in_sizes[1];   // N*K
    const int N  = in_sizes[4];   // 4096
    const int K  = nw / N;        // 4096
    const int M  = nx / K;        // 8192

    signed char* xq = (signed char*)d_ws;
    signed char* wq = (signed char*)d_ws + (size_t)nx;

    quant_x_kernel<<<nx / 4 / 256, 256, 0, stream>>>(
        (const float4*)x, is, (int*)xq, nx / 4);
    quant_w_kernel<<<nw / 4 / 256, 256, 0, stream>>>(
        (const float4*)qw, (int*)wq, nw / 4);

    dim3 grid((M / BM) * (N / BN));   // 512 blocks = 2 clean CU-waves
    gemm_i8_kernel<<<grid, 512, 0, stream>>>(xq, wq, ws, is, bs, out, M, N, K);
}

// Round 4
// 388.970 us; speedup vs baseline: 1.0584x; 1.0584x over previous
//
#include <hip/hip_runtime.h>

// W8A8 quantized linear on gfx950.
// R4: faithful fine-interleaved port of the validated 256^2 8-wave schedule.
// R3 post-mortem: coarse 8-load staging burst + sched_barrier(0) pinning
// collapsed the pipeline (MfmaUtil 34%). R4: 2 global_load_lds per phase slot
// interleaved with MFMA clusters, region-progressive staging into the
// currently-read buffer (barrier ledger below), counted vmcnt(6) once per
// K-tile (never 0 in steady state), setprio kept, sched_barrier removed.

using v4i = __attribute__((ext_vector_type(4))) int;

typedef const __attribute__((address_space(1))) signed char gc_t;
typedef __attribute__((address_space(3))) signed char lc_t;

constexpr int BM = 256;
constexpr int BN = 256;
constexpr int BK = 128;                  // int8 elements per K-tile (128 B rows)
constexpr int TILE_BYTES = BM * BK;      // 32 KB per matrix per buffer

// ---- quantization ---------------------------------------------------------

__device__ __forceinline__ int quant4(const float4 f, float s) {
    int a = (int)fminf(fmaxf(f.x / s, -128.0f), 127.0f);
    int b = (int)fminf(fmaxf(f.y / s, -128.0f), 127.0f);
    int c = (int)fminf(fmaxf(f.z / s, -128.0f), 127.0f);
    int d = (int)fminf(fmaxf(f.w / s, -128.0f), 127.0f);
    return (a & 0xff) | ((b & 0xff) << 8) | ((c & 0xff) << 16) | ((d & 0xff) << 24);
}

__global__ void quant_x_kernel(const float4* __restrict__ x,
                               const float* __restrict__ scale,
                               int* __restrict__ out, int n4) {
    const float s = scale[0];
    int i = blockIdx.x * blockDim.x + threadIdx.x;
    if (i >= n4) return;
    out[i] = quant4(x[i], s);
}

__global__ void quant_w_kernel(const float4* __restrict__ w,
                               int* __restrict__ out, int n4) {
    int i = blockIdx.x * blockDim.x + threadIdx.x;
    if (i >= n4) return;
    float4 f = w[i];
    out[i] = ((int)f.x & 0xff) | (((int)f.y & 0xff) << 8) |
             (((int)f.z & 0xff) << 16) | (((int)f.w & 0xff) << 24);
}

// ---- int8 GEMM ------------------------------------------------------------
//
// Swizzle (R2-verified, 0 bank conflicts): LDS slot (row r, chunk c) holds
// global chunk (c ^ (r&7)); staging source chunk = (lane&7)^(lane>>3);
// fragment reads XOR the chunk back.
//
// Staging ledger (iter j reads buf[j&1]; phase p reads A-bands {0,2} for
// p<2, {1,3} for p>=2; B fully consumed into regs by close(0)):
//   slot0 (after pub):    stage tile j+1 A bands {1,3} -> buf[(j+1)&1]
//                         (bands last read iter j-1 phase 3; pub publishes)
//   slot1 (after close0): stage tile j+2 B c{0,1} -> buf[j&1] B-region
//                         (B consumed collectively at close0)
//   slot2 (after close1): stage tile j+2 B c{2,3}   (>= close0, safe)
//   slot3 (after close2): stage tile j+2 A c{0,2}   (bands 0,2 consumed
//                         collectively at close1)
// Head wait: newest 6 outstanding = tile j+2's partial staging -> vmcnt(6).

#define SA(buf_, tile_, cc_)                                                   \
    __builtin_amdgcn_global_load_lds(                                          \
        (gc_t*)(pA + (size_t)(tile_) * BK + (size_t)((cc_) * 64) * Kz),        \
        (lc_t*)(smem + (buf_) * (2 * TILE_BYTES) + (wid * 8 + (cc_) * 64) * BK),\
        16, 0, 0)

#define SB(buf_, tile_, cc_)                                                   \
    __builtin_amdgcn_global_load_lds(                                          \
        (gc_t*)(pB + (size_t)(tile_) * BK + (size_t)((cc_) * 64) * Kz),        \
        (lc_t*)(smem + (buf_) * (2 * TILE_BYTES) + TILE_BYTES +                \
                (wid * 8 + (cc_) * 64) * BK),                                  \
        16, 0, 0)

#define PHASE_READS(p_)                                                        \
    a00 = *(const v4i*)(Ab + (size_t)(wm + (2 * (p_)) * 16 + fr) * BK + coff0);\
    a01 = *(const v4i*)(Ab + (size_t)(wm + (2 * (p_)) * 16 + fr) * BK + coff1);\
    a10 = *(const v4i*)(Ab + (size_t)(wm + (2 * (p_) + 1) * 16 + fr) * BK + coff0);\
    a11 = *(const v4i*)(Ab + (size_t)(wm + (2 * (p_) + 1) * 16 + fr) * BK + coff1);

#define PHASE_MFMA(p_)                                                         \
    __builtin_amdgcn_s_setprio(1);                                             \
    _Pragma("unroll")                                                          \
    for (int nt = 0; nt < 4; ++nt)                                             \
        acc[2 * (p_)][nt] = __builtin_amdgcn_mfma_i32_16x16x64_i8(             \
            a00, bf[nt][0], acc[2 * (p_)][nt], 0, 0, 0);                       \
    _Pragma("unroll")                                                          \
    for (int nt = 0; nt < 4; ++nt)                                             \
        acc[2 * (p_) + 1][nt] = __builtin_amdgcn_mfma_i32_16x16x64_i8(         \
            a10, bf[nt][0], acc[2 * (p_) + 1][nt], 0, 0, 0);                   \
    _Pragma("unroll")                                                          \
    for (int nt = 0; nt < 4; ++nt)                                             \
        acc[2 * (p_)][nt] = __builtin_amdgcn_mfma_i32_16x16x64_i8(             \
            a01, bf[nt][1], acc[2 * (p_)][nt], 0, 0, 0);                       \
    _Pragma("unroll")                                                          \
    for (int nt = 0; nt < 4; ++nt)                                             \
        acc[2 * (p_) + 1][nt] = __builtin_amdgcn_mfma_i32_16x16x64_i8(         \
            a11, bf[nt][1], acc[2 * (p_) + 1][nt], 0, 0, 0);                   \
    __builtin_amdgcn_s_setprio(0);

__global__ __launch_bounds__(512, 2) void gemm_i8_kernel(
    const signed char* __restrict__ Aq,   // [M][K] int8
    const signed char* __restrict__ Wq,   // [N][K] int8
    const float* __restrict__ wscale,     // [N]
    const float* __restrict__ iscale,     // [1]
    const float* __restrict__ bias,       // [N]
    float* __restrict__ C,                // [M][N]
    int M, int N, int K)
{
    __shared__ signed char smem[2 * 2 * TILE_BYTES];   // 128 KB

    const int tid  = threadIdx.x;
    const int wid  = tid >> 6;            // 0..7
    const int lane = tid & 63;
    const int wm   = (wid >> 2) * 128;    // wave M offset (2 M-waves)
    const int wn   = (wid & 3) * 64;      // wave N offset (4 N-waves)

    // XCD-aware bijective block swizzle (nwg % 8 == 0 for our shapes)
    const int nwg = gridDim.x;
    int wg = blockIdx.x;
    if ((nwg & 7) == 0) wg = (wg & 7) * (nwg >> 3) + (wg >> 3);
    const int ntx = N / BN;
    const int m0 = (wg / ntx) * BM;
    const int n0 = (wg % ntx) * BN;

    // staging lane mapping (8 rows x 8 chunks per wave-inst)
    const int srow   = lane >> 3;                   // 0..7
    const int gchunk = (lane & 7) ^ srow;           // swizzled source chunk

    // MFMA fragment addressing (16x16x64 i8): row = lane&15, k-quarter = lane>>4
    const int fr = lane & 15;
    const int qh = lane >> 4;
    const int coff0 = ((0 * 4 + qh) ^ (fr & 7)) * 16;   // k-substep 0
    const int coff1 = ((1 * 4 + qh) ^ (fr & 7)) * 16;   // k-substep 1

    v4i acc[8][4];
#pragma unroll
    for (int i = 0; i < 8; ++i)
#pragma unroll
        for (int j = 0; j < 4; ++j) acc[i][j] = (v4i){0, 0, 0, 0};

    const size_t Kz = (size_t)K;
    const signed char* pA = Aq + (size_t)(m0 + wid * 8 + srow) * Kz + gchunk * 16;
    const signed char* pB = Wq + (size_t)(n0 + wid * 8 + srow) * Kz + gchunk * 16;

    const int NT = K / BK;                // 32 K-tiles

    // prologue: tile 0 complete (8 loads), then tile 1 partial: B c0-3 + A c0,c2
    // (issue order matters for the head vmcnt counting)
    SA(0, 0, 0); SA(0, 0, 1); SA(0, 0, 2); SA(0, 0, 3);
    SB(0, 0, 0); SB(0, 0, 1); SB(0, 0, 2); SB(0, 0, 3);
    SB(1, 1, 0); SB(1, 1, 1); SB(1, 1, 2); SB(1, 1, 3);
    SA(1, 1, 0); SA(1, 1, 2);

    for (int j = 0; j < NT; ++j) {
        const int cur = j & 1;
        const int nxt = cur ^ 1;
        const signed char* Ab = smem + cur * (2 * TILE_BYTES);
        const signed char* Bb = Ab + TILE_BYTES;

        // tile j must be fully in LDS; tile j+2's partial staging (6) in flight
        if (j + 1 < NT) {
            asm volatile("s_waitcnt vmcnt(6)" ::: "memory");
        } else {
            asm volatile("s_waitcnt vmcnt(0)" ::: "memory");
        }
        __builtin_amdgcn_s_barrier();          // pub: tile j visible to all

        v4i bf[4][2];                          // B frags cached for whole K-tile
        v4i a00, a01, a10, a11;                // per-phase A slice

        // ---- slot 0: B cache (8 reads) + A slice 0 (4 reads) + stage ----
#pragma unroll
        for (int nt = 0; nt < 4; ++nt) {
            const signed char* br = Bb + (size_t)(wn + nt * 16 + fr) * BK;
            bf[nt][0] = *(const v4i*)(br + coff0);
            bf[nt][1] = *(const v4i*)(br + coff1);
        }
        PHASE_READS(0);
        if (j + 1 < NT) { SA(nxt, j + 1, 1); SA(nxt, j + 1, 3); }
        __builtin_amdgcn_s_barrier();          // open0
        PHASE_MFMA(0);
        __builtin_amdgcn_s_barrier();          // close0

        // ---- slot 1 ----
        PHASE_READS(1);
        if (j + 2 < NT) { SB(cur, j + 2, 0); SB(cur, j + 2, 1); }
        __builtin_amdgcn_s_barrier();          // open1
        PHASE_MFMA(1);
        __builtin_amdgcn_s_barrier();          // close1

        // ---- slot 2 ----
        PHASE_READS(2);
        if (j + 2 < NT) { SB(cur, j + 2, 2); SB(cur, j + 2, 3); }
        __builtin_amdgcn_s_barrier();          // open2
        PHASE_MFMA(2);
        __builtin_amdgcn_s_barrier();          // close2

        // ---- slot 3 ----
        PHASE_READS(3);
        if (j + 2 < NT) { SA(cur, j + 2, 0); SA(cur, j + 2, 2); }
        __builtin_amdgcn_s_barrier();          // open3
        PHASE_MFMA(3);
        // no close3: next iteration's pub barrier closes phase 3
    }

    // ---- epilogue: dequant + bias ----
    // C/D layout (HW-verified): col = lane&15, row = qh*4 + reg
    const float is = iscale[0];
#pragma unroll
    for (int nt = 0; nt < 4; ++nt) {
        const int col = n0 + wn + nt * 16 + fr;
        const float sc = wscale[col] * is;
        const float bv = bias[col];
#pragma unroll
        for (int mt = 0; mt < 8; ++mt) {
            const size_t rbase = (size_t)(m0 + wm + mt * 16 + qh * 4);
#pragma unroll
            for (int r = 0; r < 4; ++r) {
                C[(rbase + r) * N + col] = (float)acc[mt][nt][r] * sc + bv;
            }
        }
    }
}

// ---- launch ---------------------------------------------------------------

extern "C" void kernel_launch(void* const* d_in, const int* in_sizes, int n_in,
                              void* d_out, int out_size, void* d_ws, size_t ws_size,
                              hipStream_t stream) {
    const float* x  = (const float*)d_in[0];   // [B,S,IN] fp32
    const float* qw = (const float*)d_in[1];   // [OUT,IN] fp32 (int8 values)
    const float* ws = (const float*)d_in[2];   // [OUT,1]
    const float* is = (const float*)d_in[3];   // [1]
    const float* bs = (const float*)d_in[4];   // [OUT]
    float* out = (float*)d_out;

    const int nx = in_sizes[0];   // M*K
    const int nw = in_sizes[1];   // N*K
    const int N  = in_sizes[4];   // 4096
    const int K  = nw / N;        // 4096
    const int M  = nx / K;        // 8192

    signed char* xq = (signed char*)d_ws;
    signed char* wq = (signed char*)d_ws + (size_t)nx;

    quant_x_kernel<<<nx / 4 / 256, 256, 0, stream>>>(
        (const float4*)x, is, (int*)xq, nx / 4);
    quant_w_kernel<<<nw / 4 / 256, 256, 0, stream>>>(
        (const float4*)qw, (int*)wq, nw / 4);

    dim3 grid((M / BM) * (N / BN));   // 512 blocks
    gemm_i8_kernel<<<grid, 512, 0, stream>>>(xq, wq, ws, is, bs, out, M, N, K);
}